// Round 1
// baseline (1697.762 us; speedup 1.0000x reference)
//
#include <hip/hip_runtime.h>
#include <math.h>
#include <stdint.h>

// Problem constants
#define NQ 8
#define DIMV 256
#define KCODES 1024
#define NTOK 65536              // 32*2048
#define NELEM (NTOK * DIMV)     // 16777216
#define TOKPB 64                // tokens per block in fused kernel

typedef _Float16 f16x8 __attribute__((ext_vector_type(8)));
typedef float    f32x16 __attribute__((ext_vector_type(16)));

// rotate-left-3 of a 5-bit slot index (bijective bank-spreading permutation)
__device__ __forceinline__ int rotl3(int s) { return ((s << 3) | (s >> 2)) & 31; }

// ---------------------------------------------------------------------------
// Pre-pass 1: transpose embeds [q][d][k] -> embedT [q][k][d] (fp32, for the
// quantize gather in the update phase).
// ---------------------------------------------------------------------------
__global__ __launch_bounds__(256)
void vq_transpose(const float* __restrict__ embeds, float* __restrict__ embedT) {
    const int idx = blockIdx.x * 256 + threadIdx.x;       // 0 .. 2097151
    const int q   = idx >> 18;
    const int rem = idx & 262143;
    const int k   = rem >> 8;
    const int d   = rem & 255;
    embedT[idx] = embeds[q * 262144 + d * 1024 + k];
}

// Pre-pass 2: e2[q][k] = sum_d embed[q][d][k]^2 (fp32)
__global__ __launch_bounds__(256)
void vq_e2(const float* __restrict__ embeds, float* __restrict__ e2) {
    const int idx = blockIdx.x * 256 + threadIdx.x;       // 0 .. 8191
    const int q = idx >> 10;
    const int k = idx & 1023;
    const float* e = embeds + q * 262144 + k;
    float s = 0.f;
    for (int d = 0; d < DIMV; ++d) {
        const float v = e[d * 1024];
        s += v * v;
    }
    e2[idx] = s;
}

// ---------------------------------------------------------------------------
// Pre-pass 3: split embed into fp16 hi/lo laid out as per-(layer,chunk,range)
// 4 KB images read straight into registers by the fused kernel:
//   embedB[q][chunk(16)][w(16)][part(2)][s(128)][j(8)]   (halfs)
// s = h*64 + cl ; d = chunk*16 + h*8 + j ; k = w*64 + cl
// Fragment read: lane(l32,h32), tile ct -> s = h32*64 + ct*32 + l32
// (lane-contiguous 16B slots -> one coalesced global_load_dwordx4).
// ---------------------------------------------------------------------------
__global__ __launch_bounds__(256)
void vq_embedB(const float* __restrict__ embeds, _Float16* __restrict__ embedB) {
    const int idx = blockIdx.x * 256 + threadIdx.x;       // 0 .. 4194303
    const int j    = idx & 7;
    const int s    = (idx >> 3) & 127;
    const int part = (idx >> 10) & 1;
    const int w    = (idx >> 11) & 15;
    const int c    = (idx >> 15) & 15;
    const int q    = idx >> 19;
    const int h  = s >> 6;
    const int cl = s & 63;
    const int d  = c * 16 + h * 8 + j;
    const int k  = w * 64 + cl;
    const float v = embeds[q * 262144 + d * 1024 + k];
    const _Float16 hi = (_Float16)v;
    embedB[idx] = (part == 0) ? hi : (_Float16)(v - (float)hi);
}

// ---------------------------------------------------------------------------
// Fused 8-layer VQ kernel: 1024 blocks x 1024 threads (16 waves), 64
// tokens/block. The residual lives in LDS (fp16 hi/lo) across ALL 8 layers:
// x is read once, out = x - residual_final is written once. Per layer the
// wave's 64-code B slice is loaded DIRECTLY into registers (coalesced
// dwordx4, depth-1 double-buffered prefetch).
//
// MFMA operands are SWAPPED vs the classic orientation: mfma(codes, tokens)
// puts codes in D rows and tokens in D columns, so the per-token argmin over
// this wave's 64 codes is 32 lane-local compares + ONE shfl_xor(32) half-swap
// instead of a 5-stage cross-lane reduce per output row.
// ---------------------------------------------------------------------------
// LDS layout (bytes):
//  [0,     32768)  A_hi : 64 rows x 256 d fp16; 16B-block s of row t at
//                         slot rotl3(s)^(t&31)
//  [32768, 65536)  A_lo : same layout
//  [65536, 69632)  bestS  float[16][64]
//  [69632, 73728)  bestI  int  [16][64]
//  [73728, 73984)  indF   int  [64]
//  [73984, 74048)  lossRed float[16]
//  [74048, 78144)  e2Lds  float[1024]  (current layer's code norms)
#define LDS_BYTES 78144

__global__ __launch_bounds__(1024)
void vq_fused(const float* __restrict__ x, float* __restrict__ out,
              const float* __restrict__ embedT, const float* __restrict__ e2,
              const _Float16* __restrict__ embedB,
              float* __restrict__ lossSum, int* __restrict__ counts) {
    extern __shared__ char smem[];
    _Float16* Ahi = (_Float16*)smem;
    _Float16* Alo = (_Float16*)(smem + 32768);
    float* bestS   = (float*)(smem + 65536);
    int*   bestI   = (int*)(smem + 69632);
    int*   indF    = (int*)(smem + 73728);
    float* lossRed = (float*)(smem + 73984);
    float* e2Lds   = (float*)(smem + 74048);

    const int tid    = threadIdx.x;
    const int wave   = tid >> 6;       // 0..15
    const int lane   = tid & 63;
    const int l32    = lane & 31;
    const int h32    = lane >> 5;
    const int tok0   = blockIdx.x * TOKPB;
    const int codeBase = wave * 64;

    // ---- stage x -> A hi/lo (swizzled), ONCE for all 8 layers ----
#pragma unroll
    for (int k = 0; k < 2; ++k) {
        const int si = tid + k * 1024;         // 0..2047 (t,s) pairs
        const int t  = si >> 5;
        const int s  = si & 31;
        const float4 v0 = *(const float4*)(x + (tok0 + t) * 256 + s * 8);
        const float4 v1 = *(const float4*)(x + (tok0 + t) * 256 + s * 8 + 4);
        const float vv[8] = {v0.x, v0.y, v0.z, v0.w, v1.x, v1.y, v1.z, v1.w};
        f16x8 h8, l8;
#pragma unroll
        for (int e = 0; e < 8; ++e) {
            const _Float16 hi = (_Float16)vv[e];
            h8[e] = hi;
            l8[e] = (_Float16)(vv[e] - (float)hi);
        }
        const int ss = rotl3(s) ^ (t & 31);
        ((f16x8*)(Ahi + t * 256))[ss] = h8;
        ((f16x8*)(Alo + t * 256))[ss] = l8;
    }

    // ---- 8 residual-VQ layers, residual resident in LDS ----
#pragma unroll 1
    for (int q = 0; q < NQ; ++q) {
        const _Float16* embedBq = embedB + q * 524288;
        const float*    embedTq = embedT + q * (KCODES * DIMV);

        // stage this layer's e2 into LDS (broadcast-read in score phase)
        e2Lds[tid] = e2[q * KCODES + tid];
        // barrier covers: initial/updated A writes + e2 writes
        __syncthreads();

        // ---- K-loop: B register-resident, depth-1 prefetch ----
        // acc[ct][tt]: ct = code tile (D rows), tt = token tile (D cols)
        f32x16 acc[2][2];
#pragma unroll
        for (int ct = 0; ct < 2; ++ct)
#pragma unroll
            for (int tt = 0; tt < 2; ++tt)
#pragma unroll
                for (int r = 0; r < 16; ++r) acc[ct][tt][r] = 0.f;

        const char* gBw = (const char*)embedBq + wave * 4096 + h32 * 1024 + l32 * 16;

        f16x8 bH[2][2], bL[2][2];
#pragma unroll
        for (int ct = 0; ct < 2; ++ct) {
            bH[0][ct] = *(const f16x8*)(gBw + ct * 512);
            bL[0][ct] = *(const f16x8*)(gBw + 2048 + ct * 512);
        }

#pragma unroll
        for (int c = 0; c < 16; ++c) {
            const int cur = c & 1, nxt = cur ^ 1;
            if (c < 15) {
                const char* gBn = gBw + (c + 1) * 65536;
#pragma unroll
                for (int ct = 0; ct < 2; ++ct) {
                    bH[nxt][ct] = *(const f16x8*)(gBn + ct * 512);
                    bL[nxt][ct] = *(const f16x8*)(gBn + 2048 + ct * 512);
                }
            }
            f16x8 aH[2], aL[2];
#pragma unroll
            for (int tt = 0; tt < 2; ++tt) {
                const int t  = tt * 32 + l32;
                const int ss = rotl3(2 * c + h32) ^ l32;
                aH[tt] = ((const f16x8*)(Ahi + t * 256))[ss];
                aL[tt] = ((const f16x8*)(Alo + t * 256))[ss];
            }
            // swapped operands: D[code_row][token_col]
#pragma unroll
            for (int ct = 0; ct < 2; ++ct)
#pragma unroll
                for (int tt = 0; tt < 2; ++tt) {
                    acc[ct][tt] = __builtin_amdgcn_mfma_f32_32x32x16_f16(
                        bH[cur][ct], aH[tt], acc[ct][tt], 0, 0, 0);
                    acc[ct][tt] = __builtin_amdgcn_mfma_f32_32x32x16_f16(
                        bL[cur][ct], aH[tt], acc[ct][tt], 0, 0, 0);
                    acc[ct][tt] = __builtin_amdgcn_mfma_f32_32x32x16_f16(
                        bH[cur][ct], aL[tt], acc[ct][tt], 0, 0, 0);
                }
        }

        // ---- scores + per-wave argmin (lane-local codes) ----
        // lane holds, for token tt*32+l32, code rows (r&3)+8*(r>>2)+4*h32
        // per ct tile; partner lane^32 holds the complementary 32 codes.
#pragma unroll
        for (int tt = 0; tt < 2; ++tt) {
            float bs = 3.4e38f;
            int   bi = 0x7fffffff;
#pragma unroll
            for (int ct = 0; ct < 2; ++ct)
#pragma unroll
                for (int r = 0; r < 16; ++r) {
                    const int cd = codeBase + ct * 32 + (r & 3) + 8 * (r >> 2) + 4 * h32;
                    const float sc = e2Lds[cd] - 2.0f * acc[ct][tt][r];
                    if (sc < bs || (sc == bs && cd < bi)) { bs = sc; bi = cd; }
                }
            // merge with the other 32-lane half (lexicographic)
            const float so = __shfl_xor(bs, 32);
            const int   io = __shfl_xor(bi, 32);
            if (so < bs || (so == bs && io < bi)) { bs = so; bi = io; }
            if (h32 == 0) {
                bestS[wave * 64 + tt * 32 + l32] = bs;
                bestI[wave * 64 + tt * 32 + l32] = bi;
            }
        }
        __syncthreads();

        // ---- cross-wave argmin (waves cover ascending code ranges) ----
        if (tid < 64) {
            float bs = bestS[tid];
            int   bi = bestI[tid];
            for (int w = 1; w < 16; ++w) {
                const float s2 = bestS[w * 64 + tid];
                const int   i2 = bestI[w * 64 + tid];
                if (s2 < bs || (s2 == bs && i2 < bi)) { bs = s2; bi = i2; }
            }
            indF[tid] = bi;
            atomicAdd(&counts[q * KCODES + bi], 1);
        }
        __syncthreads();

        // ---- update: r -= quantize (in LDS); loss partial ----
        {
            const int tl = tid >> 4;          // token 0..63
            const int sg = tid & 15;          // 16-dim strip
            const int csel = indF[tl];
            const float* gq = embedTq + csel * 256 + sg * 16;
            float lp = 0.f;
            f16x8* rowH = (f16x8*)(Ahi + tl * 256);
            f16x8* rowL = (f16x8*)(Alo + tl * 256);
#pragma unroll
            for (int it = 0; it < 2; ++it) {
                const int slot = rotl3(sg * 2 + it) ^ (tl & 31);
                f16x8 h8 = rowH[slot];
                f16x8 l8 = rowL[slot];
                const float4 q0 = *(const float4*)(gq + it * 8);
                const float4 q1 = *(const float4*)(gq + it * 8 + 4);
                const float qv[8] = {q0.x, q0.y, q0.z, q0.w, q1.x, q1.y, q1.z, q1.w};
#pragma unroll
                for (int e = 0; e < 8; ++e) {
                    const float rv = (float)h8[e] + (float)l8[e];
                    const float nr = rv - qv[e];
                    lp += nr * nr;
                    const _Float16 nh = (_Float16)nr;
                    h8[e] = nh;
                    l8[e] = (_Float16)(nr - (float)nh);
                }
                rowH[slot] = h8;
                rowL[slot] = l8;
            }
            // loss reduction: wave -> block -> global atomic
#pragma unroll
            for (int off = 32; off > 0; off >>= 1) lp += __shfl_down(lp, off);
            if (lane == 0) lossRed[wave] = lp;
        }
        __syncthreads();
        if (tid == 0) {
            float t = 0.f;
            for (int w = 0; w < 16; ++w) t += lossRed[w];
            atomicAdd(lossSum + q, t);
        }
        // no barrier needed: next iter's e2Lds/A writes are fenced by its
        // own __syncthreads before any conflicting read.
    }

    // ---- writeback: out = x - residual_final, coalesced ----
#pragma unroll
    for (int k = 0; k < 2; ++k) {
        const int si = tid + k * 1024;
        const int t  = si >> 5;
        const int s  = si & 31;
        const int ss = rotl3(s) ^ (t & 31);
        const f16x8 h8 = ((const f16x8*)(Ahi + t * 256))[ss];
        const f16x8 l8 = ((const f16x8*)(Alo + t * 256))[ss];
        const float4 x0 = *(const float4*)(x + (tok0 + t) * 256 + s * 8);
        const float4 x1 = *(const float4*)(x + (tok0 + t) * 256 + s * 8 + 4);
        float4 o0, o1;
        o0.x = x0.x - ((float)h8[0] + (float)l8[0]);
        o0.y = x0.y - ((float)h8[1] + (float)l8[1]);
        o0.z = x0.z - ((float)h8[2] + (float)l8[2]);
        o0.w = x0.w - ((float)h8[3] + (float)l8[3]);
        o1.x = x1.x - ((float)h8[4] + (float)l8[4]);
        o1.y = x1.y - ((float)h8[5] + (float)l8[5]);
        o1.z = x1.z - ((float)h8[6] + (float)l8[6]);
        o1.w = x1.w - ((float)h8[7] + (float)l8[7]);
        *(float4*)(out + (tok0 + t) * 256 + s * 8)     = o0;
        *(float4*)(out + (tok0 + t) * 256 + s * 8 + 4) = o1;
    }
}

// ---------------------------------------------------------------------------
// Finalize: losses + perplexities into the output tail.
// ---------------------------------------------------------------------------
__global__ __launch_bounds__(256)
void vq_finalize(const int* __restrict__ counts, const float* __restrict__ lossSum,
                 float* __restrict__ outTail) {
    const int q = blockIdx.x;
    const int tid = threadIdx.x;
    float s = 0.f;
    for (int k = tid; k < KCODES; k += 256) {
        const float p = (float)counts[q * KCODES + k] * (1.0f / 65536.0f);
        s += p * logf(p + 1e-10f);
    }
    for (int off = 32; off > 0; off >>= 1) s += __shfl_down(s, off);
    __shared__ float wpart[4];
    if ((tid & 63) == 0) wpart[tid >> 6] = s;
    __syncthreads();
    if (tid == 0) {
        outTail[q]     = lossSum[q] * (1.0f / 16777216.0f);   // mean * COMMITMENT
        outTail[8 + q] = expf(-(wpart[0] + wpart[1] + wpart[2] + wpart[3]));
    }
}

// ---------------------------------------------------------------------------
extern "C" void kernel_launch(void* const* d_in, const int* in_sizes, int n_in,
                              void* d_out, int out_size, void* d_ws, size_t ws_size,
                              hipStream_t stream) {
    const float* x      = (const float*)d_in[0];   // [32,2048,256]
    const float* embeds = (const float*)d_in[1];   // [8,256,1024]
    float* out = (float*)d_out;                    // 16777216 + 8 + 8

    // Workspace layout (float units unless noted) — residual buffer GONE:
    float* embedT   = (float*)d_ws;                     // 2,097,152
    float* e2       = embedT + 2097152;                 // 8,192
    float* lossSum  = e2 + 8192;                        // 8
    int*   counts   = (int*)(lossSum + 8);              // 8,192
    _Float16* embedB = (_Float16*)(counts + 8192);      // 4,194,304 halfs (8 MB)

    hipMemsetAsync(lossSum, 0, (8 + 8192) * sizeof(float), stream);

    vq_transpose<<<8192, 256, 0, stream>>>(embeds, embedT);
    vq_e2<<<32, 256, 0, stream>>>(embeds, e2);
    vq_embedB<<<16384, 256, 0, stream>>>(embeds, embedB);

    hipFuncSetAttribute((const void*)vq_fused,
                        hipFuncAttributeMaxDynamicSharedMemorySize, LDS_BYTES);
    vq_fused<<<NTOK / TOKPB, 1024, LDS_BYTES, stream>>>(
        x, out, embedT, e2, embedB, lossSum, counts);

    vq_finalize<<<NQ, 256, 0, stream>>>(counts, lossSum, out + NELEM);
}

// Round 4
// 1420.971 us; speedup vs baseline: 1.1948x; 1.1948x over previous
//
#include <hip/hip_runtime.h>
#include <math.h>
#include <stdint.h>

// Problem constants
#define NQ 8
#define DIMV 256
#define KCODES 1024
#define NTOK 65536              // 32*2048
#define NELEM (NTOK * DIMV)     // 16777216
#define TOKPB 64                // tokens per block in fused kernel

typedef _Float16 f16x8 __attribute__((ext_vector_type(8)));
typedef float    f32x16 __attribute__((ext_vector_type(16)));

// rotate-left-3 of a 5-bit slot index (bijective bank-spreading permutation)
__device__ __forceinline__ int rotl3(int s) { return ((s << 3) | (s >> 2)) & 31; }

// ---------------------------------------------------------------------------
// Pre-pass 1: transpose embeds [q][d][k] -> embedT [q][k][d] (fp32, for the
// quantize gather in the update phase).
// ---------------------------------------------------------------------------
__global__ __launch_bounds__(256)
void vq_transpose(const float* __restrict__ embeds, float* __restrict__ embedT) {
    const int idx = blockIdx.x * 256 + threadIdx.x;       // 0 .. 2097151
    const int q   = idx >> 18;
    const int rem = idx & 262143;
    const int k   = rem >> 8;
    const int d   = rem & 255;
    embedT[idx] = embeds[q * 262144 + d * 1024 + k];
}

// Pre-pass 2: e2[q][k] = sum_d embed[q][d][k]^2 (fp32)
__global__ __launch_bounds__(256)
void vq_e2(const float* __restrict__ embeds, float* __restrict__ e2) {
    const int idx = blockIdx.x * 256 + threadIdx.x;       // 0 .. 8191
    const int q = idx >> 10;
    const int k = idx & 1023;
    const float* e = embeds + q * 262144 + k;
    float s = 0.f;
    for (int d = 0; d < DIMV; ++d) {
        const float v = e[d * 1024];
        s += v * v;
    }
    e2[idx] = s;
}

// ---------------------------------------------------------------------------
// Pre-pass 3: split embed into fp16 hi/lo laid out as per-(layer,chunk,range)
// 4 KB images read straight into registers by the fused kernel:
//   embedB[q][chunk(16)][w(16)][part(2)][s(128)][j(8)]   (halfs)
// s = h*64 + cl ; d = chunk*16 + h*8 + j ; k = w*64 + cl
// Fragment read: lane(l32,h32), tile ct -> s = h32*64 + ct*32 + l32
// (lane-contiguous 16B slots -> one coalesced global_load_dwordx4).
// ---------------------------------------------------------------------------
__global__ __launch_bounds__(256)
void vq_embedB(const float* __restrict__ embeds, _Float16* __restrict__ embedB) {
    const int idx = blockIdx.x * 256 + threadIdx.x;       // 0 .. 4194303
    const int j    = idx & 7;
    const int s    = (idx >> 3) & 127;
    const int part = (idx >> 10) & 1;
    const int w    = (idx >> 11) & 15;
    const int c    = (idx >> 15) & 15;
    const int q    = idx >> 19;
    const int h  = s >> 6;
    const int cl = s & 63;
    const int d  = c * 16 + h * 8 + j;
    const int k  = w * 64 + cl;
    const float v = embeds[q * 262144 + d * 1024 + k];
    const _Float16 hi = (_Float16)v;
    embedB[idx] = (part == 0) ? hi : (_Float16)(v - (float)hi);
}

// ---------------------------------------------------------------------------
// Fused 8-layer VQ kernel: 1024 blocks x 1024 threads (16 waves), 64
// tokens/block. Residual lives in LDS (fp16 hi/lo) across all 8 layers.
//
// Register-pressure design (the round-2 fix): __launch_bounds__(1024) pins
// each wave to 128 unified VGPR+AGPR. The round-1 version held a 64-reg
// accumulator (acc[2][2]) leaving only 64 arch VGPRs for everything else ->
// scratch spills in the hot loop (534 MB WRITE_SIZE). Now each wave's 64
// codes are processed as TWO sequential 32-code passes: acc[2] = 32 regs
// per pass, freeing ~32 regs for a depth-2 B prefetch (3-slot rotation,
// compile-time indices) with zero spill.
// ---------------------------------------------------------------------------
// LDS layout (bytes):
//  [0,     32768)  A_hi : 64 rows x 256 d fp16; 16B-block s of row t at
//                         slot rotl3(s)^(t&31)
//  [32768, 65536)  A_lo : same layout
//  [65536, 69696)  bestS  float[16][65]  (stride 65: bank-spread)
//  [69696, 73856)  bestI  int  [16][65]
//  [73856, 74112)  indF   int  [64]
//  [74112, 74176)  lossRed float[16]
//  [74176, 78272)  e2Lds  float[1024]
#define LDS_BYTES 78272

__global__ __launch_bounds__(1024)
void vq_fused(const float* __restrict__ x, float* __restrict__ out,
              const float* __restrict__ embedT, const float* __restrict__ e2,
              const _Float16* __restrict__ embedB,
              float* __restrict__ lossSum, int* __restrict__ counts) {
    extern __shared__ char smem[];
    _Float16* Ahi = (_Float16*)smem;
    _Float16* Alo = (_Float16*)(smem + 32768);
    float* bestS   = (float*)(smem + 65536);
    int*   bestI   = (int*)(smem + 69696);
    int*   indF    = (int*)(smem + 73856);
    float* lossRed = (float*)(smem + 74112);
    float* e2Lds   = (float*)(smem + 74176);

    const int tid    = threadIdx.x;
    const int wave   = tid >> 6;       // 0..15
    const int lane   = tid & 63;
    const int l32    = lane & 31;
    const int h32    = lane >> 5;
    const int tok0   = blockIdx.x * TOKPB;
    const int codeBase = wave * 64;

    // ---- stage x -> A hi/lo (swizzled), ONCE for all 8 layers ----
#pragma unroll
    for (int k = 0; k < 2; ++k) {
        const int si = tid + k * 1024;         // 0..2047 (t,s) pairs
        const int t  = si >> 5;
        const int s  = si & 31;
        const float4 v0 = *(const float4*)(x + (tok0 + t) * 256 + s * 8);
        const float4 v1 = *(const float4*)(x + (tok0 + t) * 256 + s * 8 + 4);
        const float vv[8] = {v0.x, v0.y, v0.z, v0.w, v1.x, v1.y, v1.z, v1.w};
        f16x8 h8, l8;
#pragma unroll
        for (int e = 0; e < 8; ++e) {
            const _Float16 hi = (_Float16)vv[e];
            h8[e] = hi;
            l8[e] = (_Float16)(vv[e] - (float)hi);
        }
        const int ss = rotl3(s) ^ (t & 31);
        ((f16x8*)(Ahi + t * 256))[ss] = h8;
        ((f16x8*)(Alo + t * 256))[ss] = l8;
    }

    // ---- 8 residual-VQ layers, residual resident in LDS ----
#pragma unroll 1
    for (int q = 0; q < NQ; ++q) {
        const _Float16* embedBq = embedB + q * 524288;
        const float*    embedTq = embedT + q * (KCODES * DIMV);

        // stage this layer's e2 into LDS (broadcast-read in score phase)
        e2Lds[tid] = e2[q * KCODES + tid];
        // barrier covers: initial/updated A writes + e2 writes
        __syncthreads();

        const char* gBw = (const char*)embedBq + wave * 4096 + h32 * 1024 + l32 * 16;

        // running per-token best over this wave's 64 codes (kept across passes)
        float bsv0 = 3.4e38f, bsv1 = 3.4e38f;
        int   biv0 = 0x7fffffff, biv1 = 0x7fffffff;

        // ---- two 32-code passes: acc = 32 regs, depth-2 B prefetch ----
#pragma unroll
        for (int pass = 0; pass < 2; ++pass) {
            f32x16 acc[2];
#pragma unroll
            for (int tt = 0; tt < 2; ++tt)
#pragma unroll
                for (int r = 0; r < 16; ++r) acc[tt][r] = 0.f;

            const char* gBp = gBw + pass * 512;

            // 3-slot rotating prefetch buffer (all indices compile-time)
            f16x8 bH[3], bL[3];
            bH[0] = *(const f16x8*)(gBp);
            bL[0] = *(const f16x8*)(gBp + 2048);
            bH[1] = *(const f16x8*)(gBp + 65536);
            bL[1] = *(const f16x8*)(gBp + 65536 + 2048);

#pragma unroll
            for (int c = 0; c < 16; ++c) {
                const int cs = c % 3;
                if (c < 14) {
                    const char* gBn = gBp + (c + 2) * 65536;
                    bH[(c + 2) % 3] = *(const f16x8*)(gBn);
                    bL[(c + 2) % 3] = *(const f16x8*)(gBn + 2048);
                }
                f16x8 aH[2], aL[2];
#pragma unroll
                for (int tt = 0; tt < 2; ++tt) {
                    const int t  = tt * 32 + l32;
                    const int ss = rotl3(2 * c + h32) ^ l32;
                    aH[tt] = ((const f16x8*)(Ahi + t * 256))[ss];
                    aL[tt] = ((const f16x8*)(Alo + t * 256))[ss];
                }
                // swapped operands: D[code_row][token_col]; per-tile chain
                // order (H*H, L*H, H*L; chunks ascending) identical to the
                // verified kernel -> bit-identical scores.
#pragma unroll
                for (int tt = 0; tt < 2; ++tt) {
                    acc[tt] = __builtin_amdgcn_mfma_f32_32x32x16_f16(
                        bH[cs], aH[tt], acc[tt], 0, 0, 0);
                    acc[tt] = __builtin_amdgcn_mfma_f32_32x32x16_f16(
                        bL[cs], aH[tt], acc[tt], 0, 0, 0);
                    acc[tt] = __builtin_amdgcn_mfma_f32_32x32x16_f16(
                        bH[cs], aL[tt], acc[tt], 0, 0, 0);
                }
            }

            // scores for this pass's 32 codes; fold into running best
#pragma unroll
            for (int tt = 0; tt < 2; ++tt) {
                float bs = (tt == 0) ? bsv0 : bsv1;
                int   bi = (tt == 0) ? biv0 : biv1;
#pragma unroll
                for (int r = 0; r < 16; ++r) {
                    const int cd = codeBase + pass * 32 + (r & 3) + 8 * (r >> 2) + 4 * h32;
                    const float sc = e2Lds[cd] - 2.0f * acc[tt][r];
                    if (sc < bs || (sc == bs && cd < bi)) { bs = sc; bi = cd; }
                }
                if (tt == 0) { bsv0 = bs; biv0 = bi; } else { bsv1 = bs; biv1 = bi; }
            }
        }

        // ---- merge with the other 32-lane half, write per-wave best ----
#pragma unroll
        for (int tt = 0; tt < 2; ++tt) {
            float bs = (tt == 0) ? bsv0 : bsv1;
            int   bi = (tt == 0) ? biv0 : biv1;
            const float so = __shfl_xor(bs, 32);
            const int   io = __shfl_xor(bi, 32);
            if (so < bs || (so == bs && io < bi)) { bs = so; bi = io; }
            if (h32 == 0) {
                bestS[wave * 65 + tt * 32 + l32] = bs;
                bestI[wave * 65 + tt * 32 + l32] = bi;
            }
        }
        __syncthreads();

        // ---- cross-wave argmin: 256 threads, 4 waves' entries each ----
        if (tid < 256) {
            const int t = tid >> 2;           // token 0..63
            const int g = tid & 3;            // wave-group
            float bs = 3.4e38f;
            int   bi = 0x7fffffff;
#pragma unroll
            for (int i = 0; i < 4; ++i) {
                const int w = g * 4 + i;
                const float s2 = bestS[w * 65 + t];
                const int   i2 = bestI[w * 65 + t];
                if (s2 < bs || (s2 == bs && i2 < bi)) { bs = s2; bi = i2; }
            }
#pragma unroll
            for (int m = 1; m < 4; m <<= 1) {
                const float so = __shfl_xor(bs, m);
                const int   io = __shfl_xor(bi, m);
                if (so < bs || (so == bs && io < bi)) { bs = so; bi = io; }
            }
            if (g == 0) {
                indF[t] = bi;
                atomicAdd(&counts[q * KCODES + bi], 1);
            }
        }
        __syncthreads();

        // ---- update: r -= quantize (in LDS); loss partial ----
        {
            const int tl = tid >> 4;          // token 0..63
            const int sg = tid & 15;          // 16-dim strip
            const int csel = indF[tl];
            const float* gq = embedTq + csel * 256 + sg * 16;
            float lp = 0.f;
            f16x8* rowH = (f16x8*)(Ahi + tl * 256);
            f16x8* rowL = (f16x8*)(Alo + tl * 256);
#pragma unroll
            for (int it = 0; it < 2; ++it) {
                const int slot = rotl3(sg * 2 + it) ^ (tl & 31);
                f16x8 h8 = rowH[slot];
                f16x8 l8 = rowL[slot];
                const float4 q0 = *(const float4*)(gq + it * 8);
                const float4 q1 = *(const float4*)(gq + it * 8 + 4);
                const float qv[8] = {q0.x, q0.y, q0.z, q0.w, q1.x, q1.y, q1.z, q1.w};
#pragma unroll
                for (int e = 0; e < 8; ++e) {
                    const float rv = (float)h8[e] + (float)l8[e];
                    const float nr = rv - qv[e];
                    lp += nr * nr;
                    const _Float16 nh = (_Float16)nr;
                    h8[e] = nh;
                    l8[e] = (_Float16)(nr - (float)nh);
                }
                rowH[slot] = h8;
                rowL[slot] = l8;
            }
            // loss reduction: wave -> block
#pragma unroll
            for (int off = 32; off > 0; off >>= 1) lp += __shfl_down(lp, off);
            if (lane == 0) lossRed[wave] = lp;
        }
        __syncthreads();
        if (tid < 64) {
            float v = (lane < 16) ? lossRed[lane] : 0.f;
#pragma unroll
            for (int off = 8; off > 0; off >>= 1) v += __shfl_down(v, off);
            if (lane == 0) atomicAdd(lossSum + q, v);
        }
        // next iter's e2Lds/A reads are fenced by its own __syncthreads.
    }

    // ---- writeback: out = x - residual_final, coalesced ----
#pragma unroll
    for (int k = 0; k < 2; ++k) {
        const int si = tid + k * 1024;
        const int t  = si >> 5;
        const int s  = si & 31;
        const int ss = rotl3(s) ^ (t & 31);
        const f16x8 h8 = ((const f16x8*)(Ahi + t * 256))[ss];
        const f16x8 l8 = ((const f16x8*)(Alo + t * 256))[ss];
        const float4 x0 = *(const float4*)(x + (tok0 + t) * 256 + s * 8);
        const float4 x1 = *(const float4*)(x + (tok0 + t) * 256 + s * 8 + 4);
        float4 o0, o1;
        o0.x = x0.x - ((float)h8[0] + (float)l8[0]);
        o0.y = x0.y - ((float)h8[1] + (float)l8[1]);
        o0.z = x0.z - ((float)h8[2] + (float)l8[2]);
        o0.w = x0.w - ((float)h8[3] + (float)l8[3]);
        o1.x = x1.x - ((float)h8[4] + (float)l8[4]);
        o1.y = x1.y - ((float)h8[5] + (float)l8[5]);
        o1.z = x1.z - ((float)h8[6] + (float)l8[6]);
        o1.w = x1.w - ((float)h8[7] + (float)l8[7]);
        *(float4*)(out + (tok0 + t) * 256 + s * 8)     = o0;
        *(float4*)(out + (tok0 + t) * 256 + s * 8 + 4) = o1;
    }
}

// ---------------------------------------------------------------------------
// Finalize: losses + perplexities into the output tail.
// ---------------------------------------------------------------------------
__global__ __launch_bounds__(256)
void vq_finalize(const int* __restrict__ counts, const float* __restrict__ lossSum,
                 float* __restrict__ outTail) {
    const int q = blockIdx.x;
    const int tid = threadIdx.x;
    float s = 0.f;
    for (int k = tid; k < KCODES; k += 256) {
        const float p = (float)counts[q * KCODES + k] * (1.0f / 65536.0f);
        s += p * logf(p + 1e-10f);
    }
    for (int off = 32; off > 0; off >>= 1) s += __shfl_down(s, off);
    __shared__ float wpart[4];
    if ((tid & 63) == 0) wpart[tid >> 6] = s;
    __syncthreads();
    if (tid == 0) {
        outTail[q]     = lossSum[q] * (1.0f / 16777216.0f);   // mean * COMMITMENT
        outTail[8 + q] = expf(-(wpart[0] + wpart[1] + wpart[2] + wpart[3]));
    }
}

// ---------------------------------------------------------------------------
extern "C" void kernel_launch(void* const* d_in, const int* in_sizes, int n_in,
                              void* d_out, int out_size, void* d_ws, size_t ws_size,
                              hipStream_t stream) {
    const float* x      = (const float*)d_in[0];   // [32,2048,256]
    const float* embeds = (const float*)d_in[1];   // [8,256,1024]
    float* out = (float*)d_out;                    // 16777216 + 8 + 8

    // Workspace layout (float units unless noted):
    float* embedT   = (float*)d_ws;                     // 2,097,152
    float* e2       = embedT + 2097152;                 // 8,192
    float* lossSum  = e2 + 8192;                        // 8
    int*   counts   = (int*)(lossSum + 8);              // 8,192
    _Float16* embedB = (_Float16*)(counts + 8192);      // 4,194,304 halfs (8 MB)

    hipMemsetAsync(lossSum, 0, (8 + 8192) * sizeof(float), stream);

    vq_transpose<<<8192, 256, 0, stream>>>(embeds, embedT);
    vq_e2<<<32, 256, 0, stream>>>(embeds, e2);
    vq_embedB<<<16384, 256, 0, stream>>>(embeds, embedB);

    hipFuncSetAttribute((const void*)vq_fused,
                        hipFuncAttributeMaxDynamicSharedMemorySize, LDS_BYTES);
    vq_fused<<<NTOK / TOKPB, 1024, LDS_BYTES, stream>>>(
        x, out, embedT, e2, embedB, lossSum, counts);

    vq_finalize<<<NQ, 256, 0, stream>>>(counts, lossSum, out + NELEM);
}